// Round 1
// baseline (936.816 us; speedup 1.0000x reference)
//
#include <hip/hip_runtime.h>

// B=2, T=2048, C=2048, H=16, HD=128, P=256
// Pipeline: s=mean|W| -> build WT (ternary {-1,0,1} bf16, transposed [n][k])
//           -> bf16 GEMMs for Q,K,V -> RoPE -> flash attention -> out GEMM (f32)

typedef __attribute__((ext_vector_type(8))) short short8;
typedef __attribute__((ext_vector_type(4))) float f32x4;
typedef unsigned short u16;
typedef unsigned int u32;

__device__ __forceinline__ float bf2f(u16 u) {
    u32 x = ((u32)u) << 16;
    return __builtin_bit_cast(float, x);
}
__device__ __forceinline__ u16 f2bf(float f) {
    u32 x = __builtin_bit_cast(u32, f);
    x += 0x7fffu + ((x >> 16) & 1u);   // round-to-nearest-even
    return (u16)(x >> 16);
}
__device__ __forceinline__ u32 pack2(u16 a, u16 b) { return (u32)a | ((u32)b << 16); }

__device__ const int d_OCT_IDX[8][8] = {
    {0,1,2,3,4,5,6,7},{1,0,3,2,5,4,7,6},{2,3,0,1,6,7,4,5},{3,2,1,0,7,6,5,4},
    {4,5,6,7,0,1,2,3},{5,4,7,6,1,0,3,2},{6,7,4,5,2,3,0,1},{7,6,5,4,3,2,1,0}};
__device__ const float d_OCT_SIGN[8][8] = {
    { 1, 1, 1, 1, 1, 1, 1, 1},{ 1,-1, 1,-1, 1,-1,-1, 1},{ 1,-1,-1, 1, 1, 1,-1,-1},
    { 1, 1,-1,-1, 1,-1, 1,-1},{ 1,-1,-1,-1,-1, 1, 1, 1},{ 1, 1,-1, 1,-1,-1,-1, 1},
    { 1, 1, 1,-1,-1, 1,-1,-1},{ 1,-1, 1, 1,-1,-1, 1,-1}};

// ---- s = mean(|W|) + 1e-8 for each of the 4 weights (one block per weight) ----
__global__ __launch_bounds__(1024) void reduce_s_kernel(
    const float* __restrict__ w0, const float* __restrict__ w1,
    const float* __restrict__ w2, const float* __restrict__ w3,
    float* __restrict__ s_vals) {
    __shared__ float red[1024];
    const float* W = blockIdx.x == 0 ? w0 : blockIdx.x == 1 ? w1 : blockIdx.x == 2 ? w2 : w3;
    float acc = 0.f;
    for (int idx = threadIdx.x; idx < 524288; idx += 1024) acc += fabsf(W[idx]);
    red[threadIdx.x] = acc;
    __syncthreads();
    for (int s = 512; s > 0; s >>= 1) {
        if ((int)threadIdx.x < s) red[threadIdx.x] += red[threadIdx.x + s];
        __syncthreads();
    }
    if (threadIdx.x == 0) s_vals[blockIdx.x] = red[0] / 524288.0f + 1e-8f;
}

// ---- x (f32) -> bf16, 8 elems/thread ----
__global__ __launch_bounds__(256) void cast_bf16_kernel(const float* __restrict__ X, u16* __restrict__ Xb) {
    int gid = blockIdx.x * 256 + threadIdx.x;
    const float4* X4 = (const float4*)X;
    float4 a = X4[gid * 2], b = X4[gid * 2 + 1];
    uint4 o;
    o.x = pack2(f2bf(a.x), f2bf(a.y));
    o.y = pack2(f2bf(a.z), f2bf(a.w));
    o.z = pack2(f2bf(b.x), f2bf(b.y));
    o.w = pack2(f2bf(b.z), f2bf(b.w));
    *(uint4*)&Xb[gid * 8] = o;
}

// ---- build WT[n][k] = Weff[k][n], entries exactly {-1,0,+1} in bf16 ----
// Weff[j*256+p][kblk*256+qq] = sign(i,j) * round(clip(W[i][p][qq]/s, -1, 1)), OCT_IDX[i][j]==kblk
__global__ __launch_bounds__(256) void build_weff_kernel(
    const float* __restrict__ W, const float* __restrict__ sptr, u16* __restrict__ WT) {
    int gid = blockIdx.x * 256 + threadIdx.x;
    int base = gid * 8;              // 8 consecutive k-dim entries
    int n = base >> 11;              // output col 0..2047
    int kd = base & 2047;            // input dim
    int kblk = n >> 8, qq = n & 255;
    int j = kd >> 8, p0 = kd & 255;
    int i = 0;
#pragma unroll
    for (int ii = 0; ii < 8; ii++)
        if (d_OCT_IDX[ii][j] == kblk) i = ii;
    float sign = d_OCT_SIGN[i][j];
    float s = *sptr;
    u16 r[8];
#pragma unroll
    for (int l = 0; l < 8; l++) {
        float w = W[i * 65536 + (p0 + l) * 256 + qq];
        float tq = rintf(fminf(1.f, fmaxf(-1.f, w / s)));
        r[l] = f2bf(sign * tq);      // exact in bf16
    }
    uint4 o;
    o.x = pack2(r[0], r[1]); o.y = pack2(r[2], r[3]);
    o.z = pack2(r[4], r[5]); o.w = pack2(r[6], r[7]);
    *(uint4*)&WT[(size_t)n * 2048 + kd] = o;
}

// ---- GEMM: C[M=4096][N=2048] = s * (A[M][K=2048] @ WT^T), A,WT bf16 ----
// MODE 0: write bf16 to [B][H][T][HD]  (QKV layout).  MODE 1: write f32 row-major.
template <int MODE>
__global__ __launch_bounds__(256) void gemm_kernel(
    const u16* __restrict__ A, const u16* __restrict__ Bt,
    const float* __restrict__ sptr, void* __restrict__ Cout) {
    __shared__ __align__(16) u16 As[128 * 40];  // pad 32->40 (2-way banks only)
    __shared__ __align__(16) u16 Bs[128 * 40];
    const int K = 2048;
    int tid = threadIdx.x;
    int lane = tid & 63, wid = tid >> 6;
    int quad = lane >> 4, l16 = lane & 15;
    int wm = (wid >> 1) * 64, wn = (wid & 1) * 64;
    int m0 = blockIdx.y * 128, n0 = blockIdx.x * 128;
    int srow = tid >> 2;
    int scol = (tid & 3) * 8;
    f32x4 acc[4][4];
#pragma unroll
    for (int a = 0; a < 4; a++)
#pragma unroll
        for (int b = 0; b < 4; b++) acc[a][b] = (f32x4){0.f, 0.f, 0.f, 0.f};
    const u16* Ag0 = A + (size_t)(m0 + srow) * K + scol;
    const u16* Ag1 = Ag0 + (size_t)64 * K;
    const u16* Bg0 = Bt + (size_t)(n0 + srow) * K + scol;
    const u16* Bg1 = Bg0 + (size_t)64 * K;
    for (int k0 = 0; k0 < K; k0 += 32) {
        __syncthreads();
        *(uint4*)&As[srow * 40 + scol] = *(const uint4*)(Ag0 + k0);
        *(uint4*)&As[(srow + 64) * 40 + scol] = *(const uint4*)(Ag1 + k0);
        *(uint4*)&Bs[srow * 40 + scol] = *(const uint4*)(Bg0 + k0);
        *(uint4*)&Bs[(srow + 64) * 40 + scol] = *(const uint4*)(Bg1 + k0);
        __syncthreads();
        short8 af[4], bfr[4];
#pragma unroll
        for (int mt = 0; mt < 4; mt++) af[mt] = *(const short8*)&As[(wm + mt * 16 + l16) * 40 + quad * 8];
#pragma unroll
        for (int nt = 0; nt < 4; nt++) bfr[nt] = *(const short8*)&Bs[(wn + nt * 16 + l16) * 40 + quad * 8];
#pragma unroll
        for (int mt = 0; mt < 4; mt++)
#pragma unroll
            for (int nt = 0; nt < 4; nt++)
                acc[mt][nt] = __builtin_amdgcn_mfma_f32_16x16x32_bf16(af[mt], bfr[nt], acc[mt][nt], 0, 0, 0);
    }
    float s = *sptr;
#pragma unroll
    for (int mt = 0; mt < 4; mt++)
#pragma unroll
        for (int nt = 0; nt < 4; nt++)
#pragma unroll
            for (int r = 0; r < 4; r++) {
                int m = m0 + wm + mt * 16 + quad * 4 + r;   // C/D: row=quad*4+reg
                int n = n0 + wn + nt * 16 + l16;            //      col=lane&15
                float v = acc[mt][nt][r] * s;
                if (MODE == 0) {
                    int b = m >> 11, t = m & 2047, h = n >> 7, d = n & 127;
                    ((u16*)Cout)[(size_t)((b * 16 + h) * 2048 + t) * 128 + d] = f2bf(v);
                } else {
                    ((float*)Cout)[(size_t)m * 2048 + n] = v;
                }
            }
}

// ---- interleaved RoPE in place on [B*H][T][HD] bf16 ----
__global__ __launch_bounds__(256) void rope_kernel(
    u16* __restrict__ Xb, const float* __restrict__ fc, const float* __restrict__ fs) {
    int gid = blockIdx.x * 256 + threadIdx.x;  // one (bh,t,m) pair per thread
    int m = gid & 63;
    int t = (gid >> 6) & 2047;
    u32 u = ((u32*)Xb)[gid];
    float xr = bf2f((u16)(u & 0xffff));
    float xi = bf2f((u16)(u >> 16));
    float c = fc[t * 64 + m], s = fs[t * 64 + m];
    ((u32*)Xb)[gid] = pack2(f2bf(xr * c - xi * s), f2bf(xr * s + xi * c));
}

// ---- causal flash attention: Q,K,V bf16 [B*H][T][HD] -> Y bf16 [B*T][C] ----
__global__ __launch_bounds__(256) void flash_kernel(
    const u16* __restrict__ Q, const u16* __restrict__ Kg,
    const u16* __restrict__ Vg, u16* __restrict__ Y) {
    __shared__ __align__(16) u16 Ks[64 * 136];   // [key][d], pad 128->136
    __shared__ __align__(16) u16 Vs[128 * 72];   // transposed [d][key], pad 64->72
    __shared__ __align__(16) u16 Ps[4 * 16 * 72];// per-wave P [row][key], pad
    const int T = 2048, HD = 128;
    int tid = threadIdx.x;
    int lane = tid & 63, wid = tid >> 6;
    int quad = lane >> 4, l16 = lane & 15;
    int bh = blockIdx.y;
    int q0 = blockIdx.x * 64;
    const u16* Qb = Q + (size_t)bh * T * HD;
    const u16* Kb = Kg + (size_t)bh * T * HD;
    const u16* Vb = Vg + (size_t)bh * T * HD;
    short8 qf[4];
    {
        int qrow = q0 + wid * 16 + l16;  // A-frag: m=lane&15, k=quad*8+j
#pragma unroll
        for (int kt = 0; kt < 4; kt++)
            qf[kt] = *(const short8*)&Qb[(size_t)qrow * HD + kt * 32 + quad * 8];
    }
    f32x4 o[8];
#pragma unroll
    for (int nt = 0; nt < 8; nt++) o[nt] = (f32x4){0.f, 0.f, 0.f, 0.f};
    float mrow[4] = {-1e30f, -1e30f, -1e30f, -1e30f};
    float lrow[4] = {0.f, 0.f, 0.f, 0.f};
    const float sm = 0.08838834764831845f;  // 1/sqrt(128)
    int srow_ = tid >> 4;
    int scol_ = (tid & 15) * 8;
    int nkt = (q0 >> 6) + 1;
    for (int it = 0; it < nkt; it++) {
        int s0 = it * 64;
        __syncthreads();  // protect prior-iter LDS reads
#pragma unroll
        for (int pass = 0; pass < 4; pass++) {
            int r = srow_ + pass * 16;
            *(uint4*)&Ks[r * 136 + scol_] = *(const uint4*)&Kb[(size_t)(s0 + r) * HD + scol_];
            uint4 vv = *(const uint4*)&Vb[(size_t)(s0 + r) * HD + scol_];
            u32 w_[4] = {vv.x, vv.y, vv.z, vv.w};
#pragma unroll
            for (int l = 0; l < 8; l++) {
                u16 val = (l & 1) ? (u16)(w_[l >> 1] >> 16) : (u16)(w_[l >> 1] & 0xffff);
                Vs[(scol_ + l) * 72 + r] = val;   // transpose into [d][key]
            }
        }
        __syncthreads();
        // S = Q K^T  (wave: 16 rows x 64 keys)
        f32x4 sc[4];
#pragma unroll
        for (int ct = 0; ct < 4; ct++) {
            f32x4 a = (f32x4){0.f, 0.f, 0.f, 0.f};
#pragma unroll
            for (int kt = 0; kt < 4; kt++) {
                short8 bfr = *(const short8*)&Ks[(ct * 16 + l16) * 136 + kt * 32 + quad * 8];
                a = __builtin_amdgcn_mfma_f32_16x16x32_bf16(qf[kt], bfr, a, 0, 0, 0);
            }
            sc[ct] = a;
        }
        int rowg = q0 + wid * 16 + quad * 4;
#pragma unroll
        for (int ct = 0; ct < 4; ct++) {
            int colg = s0 + ct * 16 + l16;
#pragma unroll
            for (int r = 0; r < 4; r++) {
                float v = sc[ct][r] * sm;
                sc[ct][r] = (colg > rowg + r) ? -1e30f : v;
            }
        }
        float alpha[4];
#pragma unroll
        for (int r = 0; r < 4; r++) {
            float mx = fmaxf(fmaxf(sc[0][r], sc[1][r]), fmaxf(sc[2][r], sc[3][r]));
#pragma unroll
            for (int off = 1; off < 16; off <<= 1) mx = fmaxf(mx, __shfl_xor(mx, off, 64));
            float mnew = fmaxf(mrow[r], mx);
            float a_ = __expf(mrow[r] - mnew);
            float rs = 0.f;
#pragma unroll
            for (int ct = 0; ct < 4; ct++) {
                float p = __expf(sc[ct][r] - mnew);
                sc[ct][r] = p;
                rs += p;
            }
#pragma unroll
            for (int off = 1; off < 16; off <<= 1) rs += __shfl_xor(rs, off, 64);
            mrow[r] = mnew;
            lrow[r] = lrow[r] * a_ + rs;
            alpha[r] = a_;
        }
        // P: C-layout -> LDS -> A-layout (verified m120 pattern)
        u16* Pw = &Ps[wid * 16 * 72];
#pragma unroll
        for (int ct = 0; ct < 4; ct++)
#pragma unroll
            for (int r = 0; r < 4; r++)
                Pw[(quad * 4 + r) * 72 + ct * 16 + l16] = f2bf(sc[ct][r]);
#pragma unroll
        for (int nt = 0; nt < 8; nt++) {
            f32x4 t = o[nt];
#pragma unroll
            for (int r = 0; r < 4; r++) t[r] *= alpha[r];
            o[nt] = t;
        }
        __syncthreads();  // order P writes vs cross-lane P reads
#pragma unroll
        for (int kt2 = 0; kt2 < 2; kt2++) {
            short8 pa = *(const short8*)&Pw[l16 * 72 + kt2 * 32 + quad * 8];
#pragma unroll
            for (int nt = 0; nt < 8; nt++) {
                short8 vb = *(const short8*)&Vs[(nt * 16 + l16) * 72 + kt2 * 32 + quad * 8];
                o[nt] = __builtin_amdgcn_mfma_f32_16x16x32_bf16(pa, vb, o[nt], 0, 0, 0);
            }
        }
    }
    int b = bh >> 4, h = bh & 15;
    float invl[4];
#pragma unroll
    for (int r = 0; r < 4; r++) invl[r] = 1.f / lrow[r];
#pragma unroll
    for (int nt = 0; nt < 8; nt++)
#pragma unroll
        for (int r = 0; r < 4; r++) {
            int t = q0 + wid * 16 + quad * 4 + r;
            int d = nt * 16 + l16;
            Y[(size_t)(b * T + t) * 2048 + h * 128 + d] = f2bf(o[nt][r] * invl[r]);
        }
}

extern "C" void kernel_launch(void* const* d_in, const int* in_sizes, int n_in,
                              void* d_out, int out_size, void* d_ws, size_t ws_size,
                              hipStream_t stream) {
    const float* x  = (const float*)d_in[0];
    const float* wq = (const float*)d_in[1];
    const float* wk = (const float*)d_in[2];
    const float* wv = (const float*)d_in[3];
    const float* wo = (const float*)d_in[4];
    const float* fc = (const float*)d_in[5];
    const float* fs = (const float*)d_in[6];
    float* out = (float*)d_out;

    char* ws = (char*)d_ws;
    float* s_vals = (float*)ws;                            // 16 B
    u16* WT = (u16*)(ws + 256);                            // 8 MB (reused x4)
    u16* xb = (u16*)(ws + 256 + 8388608);                  // 16 MB (x bf16, later y)
    u16* Qb = xb + 8388608;                                // 16 MB each
    u16* Kb = Qb + 8388608;
    u16* Vb = Kb + 8388608;

    reduce_s_kernel<<<4, 1024, 0, stream>>>(wq, wk, wv, wo, s_vals);
    cast_bf16_kernel<<<4096, 256, 0, stream>>>(x, xb);

    build_weff_kernel<<<2048, 256, 0, stream>>>(wq, s_vals + 0, WT);
    gemm_kernel<0><<<dim3(16, 32), 256, 0, stream>>>(xb, WT, s_vals + 0, Qb);
    rope_kernel<<<16384, 256, 0, stream>>>(Qb, fc, fs);

    build_weff_kernel<<<2048, 256, 0, stream>>>(wk, s_vals + 1, WT);
    gemm_kernel<0><<<dim3(16, 32), 256, 0, stream>>>(xb, WT, s_vals + 1, Kb);
    rope_kernel<<<16384, 256, 0, stream>>>(Kb, fc, fs);

    build_weff_kernel<<<2048, 256, 0, stream>>>(wv, s_vals + 2, WT);
    gemm_kernel<0><<<dim3(16, 32), 256, 0, stream>>>(xb, WT, s_vals + 2, Vb);

    flash_kernel<<<dim3(32, 32), 256, 0, stream>>>(Qb, Kb, Vb, xb /* y reuses xb */);

    build_weff_kernel<<<2048, 256, 0, stream>>>(wo, s_vals + 3, WT);
    gemm_kernel<1><<<dim3(16, 32), 256, 0, stream>>>(xb, WT, s_vals + 3, (void*)out);
}

// Round 2
// 594.781 us; speedup vs baseline: 1.5751x; 1.5751x over previous
//
#include <hip/hip_runtime.h>

// B=2, T=2048, C=2048, H=16, HD=128, P=256
// s=mean|W| -> WT ternary bf16 [n][k] -> async-LDS bf16 GEMMs (Q,K row-major; V transposed)
// -> RoPE (Q scaled by sm*log2e) -> 128x128 flash (swizzled LDS, P reuses K buffer) -> out GEMM

typedef __attribute__((ext_vector_type(8))) short short8;
typedef __attribute__((ext_vector_type(4))) float f32x4;
typedef unsigned short u16;
typedef unsigned int u32;

__device__ __forceinline__ float bf2f(u16 u) {
    u32 x = ((u32)u) << 16;
    return __builtin_bit_cast(float, x);
}
__device__ __forceinline__ u16 f2bf(float f) {
    u32 x = __builtin_bit_cast(u32, f);
    x += 0x7fffu + ((x >> 16) & 1u);   // RNE
    return (u16)(x >> 16);
}
__device__ __forceinline__ u16 f2bf_trunc(float f) {  // exact for {-1,0,1} and fine for p in [0,1]
    return (u16)(__builtin_bit_cast(u32, f) >> 16);
}
__device__ __forceinline__ u32 pack2(u16 a, u16 b) { return (u32)a | ((u32)b << 16); }

__device__ __forceinline__ void async16(const void* g, void* l) {
    __builtin_amdgcn_global_load_lds((const __attribute__((address_space(1))) u32*)g,
                                     (__attribute__((address_space(3))) u32*)l, 16, 0, 0);
}

__device__ const int d_OCT_IDX[8][8] = {
    {0,1,2,3,4,5,6,7},{1,0,3,2,5,4,7,6},{2,3,0,1,6,7,4,5},{3,2,1,0,7,6,5,4},
    {4,5,6,7,0,1,2,3},{5,4,7,6,1,0,3,2},{6,7,4,5,2,3,0,1},{7,6,5,4,3,2,1,0}};
__device__ const float d_OCT_SIGN[8][8] = {
    { 1, 1, 1, 1, 1, 1, 1, 1},{ 1,-1, 1,-1, 1,-1,-1, 1},{ 1,-1,-1, 1, 1, 1,-1,-1},
    { 1, 1,-1,-1, 1,-1, 1,-1},{ 1,-1,-1,-1,-1, 1, 1, 1},{ 1, 1,-1, 1,-1,-1,-1, 1},
    { 1, 1, 1,-1,-1, 1,-1,-1},{ 1,-1, 1, 1,-1,-1, 1,-1}};

// ---- stage 1: 64 partial |W| sums per weight (256 blocks total) ----
__global__ __launch_bounds__(256) void reduce1_kernel(
    const float* __restrict__ w0, const float* __restrict__ w1,
    const float* __restrict__ w2, const float* __restrict__ w3,
    float* __restrict__ partials) {
    int bid = blockIdx.x, wsel = bid >> 6, part = bid & 63;
    const float* W = wsel == 0 ? w0 : wsel == 1 ? w1 : wsel == 2 ? w2 : w3;
    int base = part * 8192 + threadIdx.x;
    float acc = 0.f;
#pragma unroll
    for (int k = 0; k < 32; k++) acc += fabsf(W[base + k * 256]);
#pragma unroll
    for (int off = 1; off < 64; off <<= 1) acc += __shfl_xor(acc, off, 64);
    __shared__ float r4[4];
    if ((threadIdx.x & 63) == 0) r4[threadIdx.x >> 6] = acc;
    __syncthreads();
    if (threadIdx.x == 0) partials[bid] = r4[0] + r4[1] + r4[2] + r4[3];
}
__global__ __launch_bounds__(256) void reduce2_kernel(const float* __restrict__ partials,
                                                      float* __restrict__ s_vals) {
    int w = threadIdx.x >> 6, lane = threadIdx.x & 63;
    float v = partials[w * 64 + lane];
#pragma unroll
    for (int off = 1; off < 64; off <<= 1) v += __shfl_xor(v, off, 64);
    if (lane == 0) s_vals[w] = v / 524288.0f + 1e-8f;
}

// ---- x (f32) -> bf16 ----
__global__ __launch_bounds__(256) void cast_bf16_kernel(const float* __restrict__ X, u16* __restrict__ Xb) {
    int gid = blockIdx.x * 256 + threadIdx.x;
    const float4* X4 = (const float4*)X;
    float4 a = X4[gid * 2], b = X4[gid * 2 + 1];
    uint4 o;
    o.x = pack2(f2bf(a.x), f2bf(a.y));
    o.y = pack2(f2bf(a.z), f2bf(a.w));
    o.z = pack2(f2bf(b.x), f2bf(b.y));
    o.w = pack2(f2bf(b.z), f2bf(b.w));
    *(uint4*)&Xb[gid * 8] = o;
}

// ---- WT[n][k]: coalesced via LDS 64x64 tile transpose. 1024 blocks. ----
__global__ __launch_bounds__(256) void build_weff_kernel(
    const float* __restrict__ W, const float* __restrict__ sptr, u16* __restrict__ WT) {
    __shared__ float Tt[64 * 68];
    int tid = threadIdx.x;
    int combo = blockIdx.x >> 4, sub = blockIdx.x & 15;
    int j = combo >> 3, kblk = combo & 7;
    int i = 0;
#pragma unroll
    for (int ii = 0; ii < 8; ii++)
        if (d_OCT_IDX[ii][j] == kblk) i = ii;
    float sign = d_OCT_SIGN[i][j];
    int p0 = (sub >> 2) * 64, q0 = (sub & 3) * 64;
    float inv_s = 1.0f / (*sptr);
#pragma unroll
    for (int pass = 0; pass < 4; pass++) {
        int p = p0 + pass * 16 + (tid >> 4);
        int q = q0 + (tid & 15) * 4;
        float4 wv = *(const float4*)&W[i * 65536 + p * 256 + q];
        float* Tp = &Tt[(pass * 16 + (tid >> 4)) * 68 + (tid & 15) * 4];
        Tp[0] = sign * rintf(fminf(1.f, fmaxf(-1.f, wv.x * inv_s)));
        Tp[1] = sign * rintf(fminf(1.f, fmaxf(-1.f, wv.y * inv_s)));
        Tp[2] = sign * rintf(fminf(1.f, fmaxf(-1.f, wv.z * inv_s)));
        Tp[3] = sign * rintf(fminf(1.f, fmaxf(-1.f, wv.w * inv_s)));
    }
    __syncthreads();
#pragma unroll
    for (int pass = 0; pass < 2; pass++) {
        int qq = pass * 32 + (tid >> 3);
        int pl = (tid & 7) * 8;
        u16 r[8];
#pragma unroll
        for (int l = 0; l < 8; l++) r[l] = f2bf_trunc(Tt[(pl + l) * 68 + qq]);
        uint4 o;
        o.x = pack2(r[0], r[1]); o.y = pack2(r[2], r[3]);
        o.z = pack2(r[4], r[5]); o.w = pack2(r[6], r[7]);
        *(uint4*)&WT[(size_t)(kblk * 256 + q0 + qq) * 2048 + j * 256 + p0 + pl] = o;
    }
}

// ---- GEMM: C[4096][2048] = s*(A @ WT^T), m97-style async staging, swizzled LDS ----
// MODE 0: bf16 row-major [m][2048]; MODE 1: f32 row-major; MODE 2: bf16 VT[(b*16+h)*128+d][t]
template <int MODE>
__global__ __launch_bounds__(256) void gemm_kernel(
    const u16* __restrict__ A, const u16* __restrict__ Bt,
    const float* __restrict__ sptr, void* __restrict__ Cout) {
    __shared__ __align__(16) u16 As[128 * 32];
    __shared__ __align__(16) u16 Bs[128 * 32];
    const int K = 2048;
    int tid = threadIdx.x, lane = tid & 63, wid = tid >> 6;
    int quad = lane >> 4, l16 = lane & 15;
    int wm = (wid >> 1) * 64, wn = (wid & 1) * 64;
    int m0 = blockIdx.y * 128, n0 = blockIdx.x * 128;
    f32x4 acc[4][4];
#pragma unroll
    for (int a = 0; a < 4; a++)
#pragma unroll
        for (int b = 0; b < 4; b++) acc[a][b] = (f32x4){0.f, 0.f, 0.f, 0.f};
    int srow = lane >> 2;                    // row within 16-row chunk
    int sblk = (lane & 3) ^ (srow & 3);      // swizzled source block
    const u16* Ag = A + (size_t)(m0 + wid * 32 + srow) * K + sblk * 8;
    const u16* Bg = Bt + (size_t)(n0 + wid * 32 + srow) * K + sblk * 8;
    u16* Al = &As[(wid * 32) * 32];
    u16* Bl = &Bs[(wid * 32) * 32];
    int rblk = (quad ^ (l16 & 3)) * 8;       // swizzled read block
    for (int k0 = 0; k0 < K; k0 += 32) {
        __syncthreads();
        async16(Ag + k0, Al);
        async16(Ag + k0 + (size_t)16 * K, Al + 16 * 32);
        async16(Bg + k0, Bl);
        async16(Bg + k0 + (size_t)16 * K, Bl + 16 * 32);
        __syncthreads();
        short8 af[4], bfv[4];
#pragma unroll
        for (int mt = 0; mt < 4; mt++) af[mt] = *(const short8*)&As[(wm + mt * 16 + l16) * 32 + rblk];
#pragma unroll
        for (int nt = 0; nt < 4; nt++) bfv[nt] = *(const short8*)&Bs[(wn + nt * 16 + l16) * 32 + rblk];
#pragma unroll
        for (int mt = 0; mt < 4; mt++)
#pragma unroll
            for (int nt = 0; nt < 4; nt++)
                acc[mt][nt] = __builtin_amdgcn_mfma_f32_16x16x32_bf16(af[mt], bfv[nt], acc[mt][nt], 0, 0, 0);
    }
    float s = *sptr;
#pragma unroll
    for (int mt = 0; mt < 4; mt++)
#pragma unroll
        for (int nt = 0; nt < 4; nt++) {
            int mg = m0 + wm + mt * 16 + quad * 4;   // +r ; C/D row=quad*4+reg
            int ng = n0 + wn + nt * 16 + l16;        // col=lane&15
            if (MODE == 0) {
#pragma unroll
                for (int r = 0; r < 4; r++)
                    ((u16*)Cout)[(size_t)(mg + r) * 2048 + ng] = f2bf(acc[mt][nt][r] * s);
            } else if (MODE == 1) {
#pragma unroll
                for (int r = 0; r < 4; r++)
                    ((float*)Cout)[(size_t)(mg + r) * 2048 + ng] = acc[mt][nt][r] * s;
            } else {
                ushort4 o4;
                o4.x = f2bf(acc[mt][nt][0] * s);
                o4.y = f2bf(acc[mt][nt][1] * s);
                o4.z = f2bf(acc[mt][nt][2] * s);
                o4.w = f2bf(acc[mt][nt][3] * s);
                // VT[(b*16+h)*128 + d][t], 4 consecutive t
                *(ushort4*)&((u16*)Cout)[((size_t)((mg >> 11) * 16 + (ng >> 7)) * 128 + (ng & 127)) * 2048 + (mg & 2047)] = o4;
            }
        }
}

// ---- interleaved RoPE in place on row-major [b*t][2048]; scale folds sm*log2e into Q ----
__global__ __launch_bounds__(256) void rope_kernel(
    u16* __restrict__ Xb, const float* __restrict__ fc, const float* __restrict__ fs, float scale) {
    int gid = blockIdx.x * 256 + threadIdx.x;
    int c2 = gid & 1023;          // column pair 0..1023
    int t = (gid >> 10) & 2047;
    int m = c2 & 63;              // d/2 within head
    u32 u = ((u32*)Xb)[gid];
    float xr = bf2f((u16)(u & 0xffff));
    float xi = bf2f((u16)(u >> 16));
    float c = fc[t * 64 + m] * scale, s = fs[t * 64 + m] * scale;
    ((u32*)Xb)[gid] = pack2(f2bf(xr * c - xi * s), f2bf(xr * s + xi * c));
}

// ---- flash attention, 128Q x 128K tiles, swizzled 64KB LDS, P reuses Ks ----
// Q,K row-major [b*2048+t][2048] (Q pre-scaled by sm*log2e); VT [(b*16+h)*128+d][t]
// Y (=Q buffer, per-block self-aliasing is safe) row-major bf16 [b*2048+t][2048]
__global__ __launch_bounds__(256, 2) void flash_kernel(
    const u16* __restrict__ Q, const u16* __restrict__ Kg,
    const u16* __restrict__ VTg, u16* __restrict__ Y) {
    __shared__ __align__(16) u16 Ks[128 * 128];  // [key][d] swizzled; reused as P [row][key]
    __shared__ __align__(16) u16 Vs[128 * 128];  // [d][key] swizzled
    int tid = threadIdx.x, lane = tid & 63, wid = tid >> 6;
    int quad = lane >> 4, l16 = lane & 15;
    int bh = blockIdx.y, b = bh >> 4, h = bh & 15;
    int qt = 15 - blockIdx.x;     // long blocks first (LPT)
    int q0 = qt * 128;
    int wrow = wid * 32;
    const u16* Qb = Q + ((size_t)b * 2048) * 2048 + h * 128;
    const u16* Kb = Kg + ((size_t)b * 2048) * 2048 + h * 128;
    const u16* Vb = VTg + ((size_t)bh * 128) * 2048;
    short8 qf[2][4];
#pragma unroll
    for (int mt = 0; mt < 2; mt++)
#pragma unroll
        for (int kt = 0; kt < 4; kt++)
            qf[mt][kt] = *(const short8*)&Qb[(size_t)(q0 + wrow + mt * 16 + l16) * 2048 + kt * 32 + quad * 8];
    f32x4 o[2][8];
#pragma unroll
    for (int mt = 0; mt < 2; mt++)
#pragma unroll
        for (int nt = 0; nt < 8; nt++) o[mt][nt] = (f32x4){0.f, 0.f, 0.f, 0.f};
    float m_[2][4], l_[2][4];
#pragma unroll
    for (int mt = 0; mt < 2; mt++)
#pragma unroll
        for (int r = 0; r < 4; r++) { m_[mt][r] = -1e30f; l_[mt][r] = 0.f; }
    int srow4 = lane >> 4;   // row within 4-row chunk
    int sblk = lane & 15;
    int niter = qt + 1;
    for (int it = 0; it < niter; it++) {
        int s0 = it * 128;
        __syncthreads();  // prior-iter P/V reads done before staging overwrites
#pragma unroll
        for (int cc = 0; cc < 8; cc++) {
            int ch = wid * 8 + cc;
            int row = ch * 4 + srow4;             // local row 0..127
            int gb = sblk ^ (row & 15);           // source-side swizzle
            async16(&Kb[(size_t)(s0 + row) * 2048 + gb * 8], &Ks[ch * 512]);
            async16(&Vb[(size_t)row * 2048 + s0 + gb * 8], &Vs[ch * 512]);
        }
        __syncthreads();
        // S = Q K^T : per wave 32 rows x 128 keys
        f32x4 sc[2][8];
#pragma unroll
        for (int ct = 0; ct < 8; ct++) {
            short8 bfv[4];
#pragma unroll
            for (int kt = 0; kt < 4; kt++)
                bfv[kt] = *(const short8*)&Ks[(ct * 16 + l16) * 128 + (((kt * 4 + quad) ^ l16)) * 8];
#pragma unroll
            for (int mt = 0; mt < 2; mt++) {
                f32x4 a = (mt == 0) ? (f32x4){0.f, 0.f, 0.f, 0.f} : (f32x4){0.f, 0.f, 0.f, 0.f};
#pragma unroll
                for (int kt = 0; kt < 4; kt++)
                    a = __builtin_amdgcn_mfma_f32_16x16x32_bf16(qf[mt][kt], bfv[kt], a, 0, 0, 0);
                sc[mt][ct] = a;
            }
        }
        if (it == qt) {  // diagonal tile: causal mask (local row/col compare)
#pragma unroll
            for (int mt = 0; mt < 2; mt++)
#pragma unroll
                for (int ct = 0; ct < 8; ct++) {
                    int colg = ct * 16 + l16;
#pragma unroll
                    for (int r = 0; r < 4; r++) {
                        int rowg = wrow + mt * 16 + quad * 4 + r;
                        if (colg > rowg) sc[mt][ct][r] = -1e30f;
                    }
                }
        }
        float alpha[2][4];
#pragma unroll
        for (int mt = 0; mt < 2; mt++)
#pragma unroll
            for (int r = 0; r < 4; r++) {
                float mx = sc[mt][0][r];
#pragma unroll
                for (int ct = 1; ct < 8; ct++) mx = fmaxf(mx, sc[mt][ct][r]);
#pragma unroll
                for (int off = 1; off < 16; off <<= 1) mx = fmaxf(mx, __shfl_xor(mx, off, 64));
                float mn = fmaxf(m_[mt][r], mx);
                float al = exp2f(m_[mt][r] - mn);
                float rs = 0.f;
#pragma unroll
                for (int ct = 0; ct < 8; ct++) {
                    float p = exp2f(sc[mt][ct][r] - mn);
                    sc[mt][ct][r] = p;
                    rs += p;
                }
#pragma unroll
                for (int off = 1; off < 16; off <<= 1) rs += __shfl_xor(rs, off, 64);
                m_[mt][r] = mn;
                l_[mt][r] = l_[mt][r] * al + rs;
                alpha[mt][r] = al;
            }
        __syncthreads();  // all waves done reading Ks -> safe to overwrite with P
#pragma unroll
        for (int mt = 0; mt < 2; mt++)
#pragma unroll
            for (int ct = 0; ct < 8; ct++)
#pragma unroll
                for (int r = 0; r < 4; r++) {
                    int row = wrow + mt * 16 + quad * 4 + r;
                    int key = ct * 16 + l16;
                    int phys = (key >> 3) ^ (row & 15);
                    Ks[row * 128 + phys * 8 + (key & 7)] = f2bf_trunc(sc[mt][ct][r]);
                }
#pragma unroll
        for (int mt = 0; mt < 2; mt++)
#pragma unroll
            for (int nt = 0; nt < 8; nt++) {
                f32x4 t = o[mt][nt];
#pragma unroll
                for (int r = 0; r < 4; r++) t[r] *= alpha[mt][r];
                o[mt][nt] = t;
            }
        __syncthreads();  // P visible before A-frag reads
#pragma unroll
        for (int kt = 0; kt < 4; kt++) {
            short8 pa[2];
#pragma unroll
            for (int mt = 0; mt < 2; mt++)
                pa[mt] = *(const short8*)&Ks[(wrow + mt * 16 + l16) * 128 + (((kt * 4 + quad) ^ l16)) * 8];
#pragma unroll
            for (int nt = 0; nt < 8; nt++) {
                short8 vb = *(const short8*)&Vs[(nt * 16 + l16) * 128 + (((kt * 4 + quad) ^ l16)) * 8];
#pragma unroll
                for (int mt = 0; mt < 2; mt++)
                    o[mt][nt] = __builtin_amdgcn_mfma_f32_16x16x32_bf16(pa[mt], vb, o[mt][nt], 0, 0, 0);
            }
        }
    }
#pragma unroll
    for (int mt = 0; mt < 2; mt++) {
        float iv[4];
#pragma unroll
        for (int r = 0; r < 4; r++) iv[r] = 1.f / l_[mt][r];
#pragma unroll
        for (int nt = 0; nt < 8; nt++)
#pragma unroll
            for (int r = 0; r < 4; r++) {
                int t_ = q0 + wrow + mt * 16 + quad * 4 + r;
                int d = nt * 16 + l16;
                Y[((size_t)(b * 2048 + t_)) * 2048 + h * 128 + d] = f2bf(o[mt][nt][r] * iv[r]);
            }
    }
}

extern "C" void kernel_launch(void* const* d_in, const int* in_sizes, int n_in,
                              void* d_out, int out_size, void* d_ws, size_t ws_size,
                              hipStream_t stream) {
    const float* x  = (const float*)d_in[0];
    const float* wq = (const float*)d_in[1];
    const float* wk = (const float*)d_in[2];
    const float* wv = (const float*)d_in[3];
    const float* wo = (const float*)d_in[4];
    const float* fc = (const float*)d_in[5];
    const float* fs = (const float*)d_in[6];
    float* out = (float*)d_out;

    char* ws = (char*)d_ws;
    float* s_vals   = (float*)ws;                    // 16 B
    float* partials = (float*)(ws + 1024);           // 1 KB
    u16* WT  = (u16*)(ws + 8192);                    // 8 MB (reused x4)
    u16* xb  = (u16*)(ws + 8192 + 8388608);          // 16 MB
    u16* Qb  = xb + 8388608;                         // 16 MB (later aliased by Y)
    u16* Kb  = Qb + 8388608;
    u16* VTb = Kb + 8388608;

    const float QSCALE = 0.08838834764831845f * 1.4426950408889634f;  // 1/sqrt(128)*log2(e)

    reduce1_kernel<<<256, 256, 0, stream>>>(wq, wk, wv, wo, partials);
    reduce2_kernel<<<1, 256, 0, stream>>>(partials, s_vals);
    cast_bf16_kernel<<<4096, 256, 0, stream>>>(x, xb);

    build_weff_kernel<<<1024, 256, 0, stream>>>(wq, s_vals + 0, WT);
    gemm_kernel<0><<<dim3(16, 32), 256, 0, stream>>>(xb, WT, s_vals + 0, Qb);
    rope_kernel<<<16384, 256, 0, stream>>>(Qb, fc, fs, QSCALE);

    build_weff_kernel<<<1024, 256, 0, stream>>>(wk, s_vals + 1, WT);
    gemm_kernel<0><<<dim3(16, 32), 256, 0, stream>>>(xb, WT, s_vals + 1, Kb);
    rope_kernel<<<16384, 256, 0, stream>>>(Kb, fc, fs, 1.0f);

    build_weff_kernel<<<1024, 256, 0, stream>>>(wv, s_vals + 2, WT);
    gemm_kernel<2><<<dim3(16, 32), 256, 0, stream>>>(xb, WT, s_vals + 2, VTb);

    flash_kernel<<<dim3(16, 32), 256, 0, stream>>>(Qb, Kb, VTb, Qb /* Y aliases Q: per-block safe */);

    build_weff_kernel<<<1024, 256, 0, stream>>>(wo, s_vals + 3, WT);
    gemm_kernel<1><<<dim3(16, 32), 256, 0, stream>>>(Qb, WT, s_vals + 3, (void*)out);
}

// Round 3
// 414.622 us; speedup vs baseline: 2.2594x; 1.4345x over previous
//
#include <hip/hip_runtime.h>

// B=2, T=2048, C=2048, H=16, HD=128, P=256
// s=mean|W| -> WT ternary bf16 [n][k] -> async-LDS bf16 GEMMs (Q,K row-major; V transposed)
// -> RoPE (Q scaled by sm*log2e) -> folded dbuf flash (1 barrier/iter) -> out GEMM

typedef __attribute__((ext_vector_type(8))) short short8;
typedef __attribute__((ext_vector_type(4))) float f32x4;
typedef unsigned short u16;
typedef unsigned int u32;

__device__ __forceinline__ float bf2f(u16 u) {
    u32 x = ((u32)u) << 16;
    return __builtin_bit_cast(float, x);
}
__device__ __forceinline__ u16 f2bf(float f) {
    u32 x = __builtin_bit_cast(u32, f);
    x += 0x7fffu + ((x >> 16) & 1u);   // RNE
    return (u16)(x >> 16);
}
__device__ __forceinline__ u16 f2bf_trunc(float f) {
    return (u16)(__builtin_bit_cast(u32, f) >> 16);
}
__device__ __forceinline__ u32 pack2(u16 a, u16 b) { return (u32)a | ((u32)b << 16); }

__device__ __forceinline__ void async16(const void* g, void* l) {
    __builtin_amdgcn_global_load_lds((const __attribute__((address_space(1))) u32*)g,
                                     (__attribute__((address_space(3))) u32*)l, 16, 0, 0);
}

__device__ const int d_OCT_IDX[8][8] = {
    {0,1,2,3,4,5,6,7},{1,0,3,2,5,4,7,6},{2,3,0,1,6,7,4,5},{3,2,1,0,7,6,5,4},
    {4,5,6,7,0,1,2,3},{5,4,7,6,1,0,3,2},{6,7,4,5,2,3,0,1},{7,6,5,4,3,2,1,0}};
__device__ const float d_OCT_SIGN[8][8] = {
    { 1, 1, 1, 1, 1, 1, 1, 1},{ 1,-1, 1,-1, 1,-1,-1, 1},{ 1,-1,-1, 1, 1, 1,-1,-1},
    { 1, 1,-1,-1, 1,-1, 1,-1},{ 1,-1,-1,-1,-1, 1, 1, 1},{ 1, 1,-1, 1,-1,-1,-1, 1},
    { 1, 1, 1,-1,-1, 1,-1,-1},{ 1,-1, 1, 1,-1,-1, 1,-1}};

// ---- stage 1: 64 partial |W| sums per weight ----
__global__ __launch_bounds__(256) void reduce1_kernel(
    const float* __restrict__ w0, const float* __restrict__ w1,
    const float* __restrict__ w2, const float* __restrict__ w3,
    float* __restrict__ partials) {
    int bid = blockIdx.x, wsel = bid >> 6, part = bid & 63;
    const float* W = wsel == 0 ? w0 : wsel == 1 ? w1 : wsel == 2 ? w2 : w3;
    int base = part * 8192 + threadIdx.x;
    float acc = 0.f;
#pragma unroll
    for (int k = 0; k < 32; k++) acc += fabsf(W[base + k * 256]);
#pragma unroll
    for (int off = 1; off < 64; off <<= 1) acc += __shfl_xor(acc, off, 64);
    __shared__ float r4[4];
    if ((threadIdx.x & 63) == 0) r4[threadIdx.x >> 6] = acc;
    __syncthreads();
    if (threadIdx.x == 0) partials[bid] = r4[0] + r4[1] + r4[2] + r4[3];
}
__global__ __launch_bounds__(256) void reduce2_kernel(const float* __restrict__ partials,
                                                      float* __restrict__ s_vals) {
    int w = threadIdx.x >> 6, lane = threadIdx.x & 63;
    float v = partials[w * 64 + lane];
#pragma unroll
    for (int off = 1; off < 64; off <<= 1) v += __shfl_xor(v, off, 64);
    if (lane == 0) s_vals[w] = v / 524288.0f + 1e-8f;
}

// ---- x (f32) -> bf16 ----
__global__ __launch_bounds__(256) void cast_bf16_kernel(const float* __restrict__ X, u16* __restrict__ Xb) {
    int gid = blockIdx.x * 256 + threadIdx.x;
    const float4* X4 = (const float4*)X;
    float4 a = X4[gid * 2], b = X4[gid * 2 + 1];
    uint4 o;
    o.x = pack2(f2bf(a.x), f2bf(a.y));
    o.y = pack2(f2bf(a.z), f2bf(a.w));
    o.z = pack2(f2bf(b.x), f2bf(b.y));
    o.w = pack2(f2bf(b.z), f2bf(b.w));
    *(uint4*)&Xb[gid * 8] = o;
}

// ---- WT[n][k]: coalesced via LDS 64x64 tile transpose ----
__global__ __launch_bounds__(256) void build_weff_kernel(
    const float* __restrict__ W, const float* __restrict__ sptr, u16* __restrict__ WT) {
    __shared__ float Tt[64 * 68];
    int tid = threadIdx.x;
    int combo = blockIdx.x >> 4, sub = blockIdx.x & 15;
    int j = combo >> 3, kblk = combo & 7;
    int i = 0;
#pragma unroll
    for (int ii = 0; ii < 8; ii++)
        if (d_OCT_IDX[ii][j] == kblk) i = ii;
    float sign = d_OCT_SIGN[i][j];
    int p0 = (sub >> 2) * 64, q0 = (sub & 3) * 64;
    float inv_s = 1.0f / (*sptr);
#pragma unroll
    for (int pass = 0; pass < 4; pass++) {
        int p = p0 + pass * 16 + (tid >> 4);
        int q = q0 + (tid & 15) * 4;
        float4 wv = *(const float4*)&W[i * 65536 + p * 256 + q];
        float* Tp = &Tt[(pass * 16 + (tid >> 4)) * 68 + (tid & 15) * 4];
        Tp[0] = sign * rintf(fminf(1.f, fmaxf(-1.f, wv.x * inv_s)));
        Tp[1] = sign * rintf(fminf(1.f, fmaxf(-1.f, wv.y * inv_s)));
        Tp[2] = sign * rintf(fminf(1.f, fmaxf(-1.f, wv.z * inv_s)));
        Tp[3] = sign * rintf(fminf(1.f, fmaxf(-1.f, wv.w * inv_s)));
    }
    __syncthreads();
#pragma unroll
    for (int pass = 0; pass < 2; pass++) {
        int qq = pass * 32 + (tid >> 3);
        int pl = (tid & 7) * 8;
        u16 r[8];
#pragma unroll
        for (int l = 0; l < 8; l++) r[l] = f2bf_trunc(Tt[(pl + l) * 68 + qq]);
        uint4 o;
        o.x = pack2(r[0], r[1]); o.y = pack2(r[2], r[3]);
        o.z = pack2(r[4], r[5]); o.w = pack2(r[6], r[7]);
        *(uint4*)&WT[(size_t)(kblk * 256 + q0 + qq) * 2048 + j * 256 + p0 + pl] = o;
    }
}

// ---- GEMM: C[4096][2048] = s*(A @ WT^T) ----
// MODE 0: bf16 row-major; MODE 1: f32 row-major; MODE 2: bf16 VT[(b*16+h)*128+d][t]
template <int MODE>
__global__ __launch_bounds__(256) void gemm_kernel(
    const u16* __restrict__ A, const u16* __restrict__ Bt,
    const float* __restrict__ sptr, void* __restrict__ Cout) {
    __shared__ __align__(16) u16 As[128 * 32];
    __shared__ __align__(16) u16 Bs[128 * 32];
    const int K = 2048;
    int tid = threadIdx.x, lane = tid & 63, wid = tid >> 6;
    int quad = lane >> 4, l16 = lane & 15;
    int wm = (wid >> 1) * 64, wn = (wid & 1) * 64;
    int m0 = blockIdx.y * 128, n0 = blockIdx.x * 128;
    f32x4 acc[4][4];
#pragma unroll
    for (int a = 0; a < 4; a++)
#pragma unroll
        for (int b = 0; b < 4; b++) acc[a][b] = (f32x4){0.f, 0.f, 0.f, 0.f};
    int srow = lane >> 2;
    int sblk = (lane & 3) ^ (srow & 3);
    const u16* Ag = A + (size_t)(m0 + wid * 32 + srow) * K + sblk * 8;
    const u16* Bg = Bt + (size_t)(n0 + wid * 32 + srow) * K + sblk * 8;
    u16* Al = &As[(wid * 32) * 32];
    u16* Bl = &Bs[(wid * 32) * 32];
    int rblk = (quad ^ (l16 & 3)) * 8;
    for (int k0 = 0; k0 < K; k0 += 32) {
        __syncthreads();
        async16(Ag + k0, Al);
        async16(Ag + k0 + (size_t)16 * K, Al + 16 * 32);
        async16(Bg + k0, Bl);
        async16(Bg + k0 + (size_t)16 * K, Bl + 16 * 32);
        __syncthreads();
        short8 af[4], bfv[4];
#pragma unroll
        for (int mt = 0; mt < 4; mt++) af[mt] = *(const short8*)&As[(wm + mt * 16 + l16) * 32 + rblk];
#pragma unroll
        for (int nt = 0; nt < 4; nt++) bfv[nt] = *(const short8*)&Bs[(wn + nt * 16 + l16) * 32 + rblk];
#pragma unroll
        for (int mt = 0; mt < 4; mt++)
#pragma unroll
            for (int nt = 0; nt < 4; nt++)
                acc[mt][nt] = __builtin_amdgcn_mfma_f32_16x16x32_bf16(af[mt], bfv[nt], acc[mt][nt], 0, 0, 0);
    }
    float s = *sptr;
#pragma unroll
    for (int mt = 0; mt < 4; mt++)
#pragma unroll
        for (int nt = 0; nt < 4; nt++) {
            int mg = m0 + wm + mt * 16 + quad * 4;
            int ng = n0 + wn + nt * 16 + l16;
            if (MODE == 0) {
#pragma unroll
                for (int r = 0; r < 4; r++)
                    ((u16*)Cout)[(size_t)(mg + r) * 2048 + ng] = f2bf(acc[mt][nt][r] * s);
            } else if (MODE == 1) {
#pragma unroll
                for (int r = 0; r < 4; r++)
                    ((float*)Cout)[(size_t)(mg + r) * 2048 + ng] = acc[mt][nt][r] * s;
            } else {
                ushort4 o4;
                o4.x = f2bf(acc[mt][nt][0] * s);
                o4.y = f2bf(acc[mt][nt][1] * s);
                o4.z = f2bf(acc[mt][nt][2] * s);
                o4.w = f2bf(acc[mt][nt][3] * s);
                *(ushort4*)&((u16*)Cout)[((size_t)((mg >> 11) * 16 + (ng >> 7)) * 128 + (ng & 127)) * 2048 + (mg & 2047)] = o4;
            }
        }
}

// ---- interleaved RoPE in place; scale folds sm*log2e into Q ----
__global__ __launch_bounds__(256) void rope_kernel(
    u16* __restrict__ Xb, const float* __restrict__ fc, const float* __restrict__ fs, float scale) {
    int gid = blockIdx.x * 256 + threadIdx.x;
    int c2 = gid & 1023;
    int t = (gid >> 10) & 2047;
    int m = c2 & 63;
    u32 u = ((u32*)Xb)[gid];
    float xr = bf2f((u16)(u & 0xffff));
    float xi = bf2f((u16)(u >> 16));
    float c = fc[t * 64 + m] * scale, s = fs[t * 64 + m] * scale;
    ((u32*)Xb)[gid] = pack2(f2bf(xr * c - xi * s), f2bf(xr * s + xi * c));
}

// ---- folded, double-buffered flash: block = (bh, qt-pair), 8 waves, 34 iters each ----
// Q,K row-major (Q pre-scaled by sm*log2e); VT [(b*16+h)*128+d][t]; Y row-major bf16 (aliases Q)
__global__ __launch_bounds__(512, 2) void flash_kernel(
    const u16* __restrict__ Q, const u16* __restrict__ Kg,
    const u16* __restrict__ VTg, u16* __restrict__ Y) {
    __shared__ __align__(16) u16 Ks[2][64 * 128];   // [key][d], XOR-swizzled
    __shared__ __align__(16) u16 Vs[2][128 * 64];   // [d][key], XOR-swizzled
    __shared__ __align__(16) u16 Ps[8 * 16 * 64];   // wave-private P, XOR-swizzled
    const int NIT = 34;
    int tid = threadIdx.x, lane = tid & 63, wid = tid >> 6;   // 8 waves
    int quad = lane >> 4, l16 = lane & 15;
    int bh = blockIdx.x, b = bh >> 4, h = bh & 15;            // x=bh: same-head blocks share XCD L2
    int qt = blockIdx.y;                                      // 0..7 -> tile pair (qt, 15-qt)
    int nitA = 2 * qt + 2;
    const u16* Qb = Q + (size_t)b * 2048 * 2048 + h * 128;
    const u16* Kb = Kg + (size_t)b * 2048 * 2048 + h * 128;
    const u16* Vb = VTg + (size_t)bh * 128 * 2048;
    int q0 = qt * 128, nit = nitA;
    int ksr = lane >> 4, ksb = lane & 15;   // K staging geometry
    int vsr = lane >> 3, vsb = lane & 7;    // V staging geometry
    // prologue: tile 0 -> buf 0
#pragma unroll
    for (int cc = 0; cc < 2; cc++) {
        int ch = wid * 2 + cc;
        int kr = ch * 4 + ksr;
        async16(&Kb[(size_t)kr * 2048 + (ksb ^ (kr & 15)) * 8], &Ks[0][ch * 512]);
        int vd = ch * 8 + vsr;
        async16(&Vb[(size_t)vd * 2048 + (vsb ^ (vd & 7)) * 8], &Vs[0][ch * 512]);
    }
    short8 qf[4];
#pragma unroll
    for (int kt = 0; kt < 4; kt++)
        qf[kt] = *(const short8*)&Qb[(size_t)(q0 + wid * 16 + l16) * 2048 + kt * 32 + quad * 8];
    f32x4 o[8];
#pragma unroll
    for (int nt = 0; nt < 8; nt++) o[nt] = (f32x4){0.f, 0.f, 0.f, 0.f};
    float m_[4] = {-1e30f, -1e30f, -1e30f, -1e30f};
    float l_[4] = {0.f, 0.f, 0.f, 0.f};
    int il = 0;
    for (int g = 0; g < NIT; g++) {
        int c = g & 1;
        __syncthreads();   // single barrier: drains prefetch (issued 1 full iter ago), orders buf reuse
        if (g + 1 < NIT) {
            int gn = g + 1;
            int s0n = (gn < nitA ? gn : gn - nitA) * 64;
#pragma unroll
            for (int cc = 0; cc < 2; cc++) {
                int ch = wid * 2 + cc;
                int kr = ch * 4 + ksr;
                async16(&Kb[(size_t)(s0n + kr) * 2048 + (ksb ^ (kr & 15)) * 8], &Ks[1 - c][ch * 512]);
                int vd = ch * 8 + vsr;
                async16(&Vb[(size_t)vd * 2048 + s0n + (vsb ^ (vd & 7)) * 8], &Vs[1 - c][ch * 512]);
            }
        }
        int s0 = il * 64;
        // S = Q K^T : wave 16 q-rows x 64 keys
        f32x4 sc[4];
#pragma unroll
        for (int ct = 0; ct < 4; ct++) {
            f32x4 a = (f32x4){0.f, 0.f, 0.f, 0.f};
#pragma unroll
            for (int kt = 0; kt < 4; kt++) {
                short8 bfv = *(const short8*)&Ks[c][(ct * 16 + l16) * 128 + ((kt * 4 + quad) ^ l16) * 8];
                a = __builtin_amdgcn_mfma_f32_16x16x32_bf16(qf[kt], bfv, a, 0, 0, 0);
            }
            sc[ct] = a;
        }
        if (il >= nit - 2) {   // diagonal tiles only
#pragma unroll
            for (int ct = 0; ct < 4; ct++) {
                int colg = s0 + ct * 16 + l16;
#pragma unroll
                for (int r = 0; r < 4; r++) {
                    int rowg = q0 + wid * 16 + quad * 4 + r;
                    if (colg > rowg) sc[ct][r] = -1e30f;
                }
            }
        }
        float alpha[4];
#pragma unroll
        for (int r = 0; r < 4; r++) {
            float mx = fmaxf(fmaxf(sc[0][r], sc[1][r]), fmaxf(sc[2][r], sc[3][r]));
#pragma unroll
            for (int off = 1; off < 16; off <<= 1) mx = fmaxf(mx, __shfl_xor(mx, off, 64));
            float mn = fmaxf(m_[r], mx);
            float al = exp2f(m_[r] - mn);
            float rs = 0.f;
#pragma unroll
            for (int ct = 0; ct < 4; ct++) {
                float p = exp2f(sc[ct][r] - mn);
                sc[ct][r] = p;
                rs += p;
            }
#pragma unroll
            for (int off = 1; off < 16; off <<= 1) rs += __shfl_xor(rs, off, 64);
            m_[r] = mn;
            l_[r] = l_[r] * al + rs;
            alpha[r] = al;
        }
        // P: C-layout -> wave-private LDS (no barrier; in-wave lgkm ordering)
        u16* Pw = &Ps[wid * 1024];
#pragma unroll
        for (int ct = 0; ct < 4; ct++)
#pragma unroll
            for (int r = 0; r < 4; r++) {
                int lr = quad * 4 + r;
                int key = ct * 16 + l16;
                Pw[lr * 64 + ((key >> 3) ^ (lr & 7)) * 8 + (key & 7)] = f2bf_trunc(sc[ct][r]);
            }
#pragma unroll
        for (int nt = 0; nt < 8; nt++)
#pragma unroll
            for (int r = 0; r < 4; r++) o[nt][r] *= alpha[r];
        // O += P V
#pragma unroll
        for (int kt2 = 0; kt2 < 2; kt2++) {
            short8 pa = *(const short8*)&Pw[l16 * 64 + ((kt2 * 4 + quad) ^ (l16 & 7)) * 8];
#pragma unroll
            for (int nt = 0; nt < 8; nt++) {
                short8 vb = *(const short8*)&Vs[c][(nt * 16 + l16) * 64 + ((kt2 * 4 + quad) ^ (l16 & 7)) * 8];
                o[nt] = __builtin_amdgcn_mfma_f32_16x16x32_bf16(pa, vb, o[nt], 0, 0, 0);
            }
        }
        il++;
        if (il == nit && g + 1 < NIT) {   // flush sub-problem A, switch to B
            float iv[4];
#pragma unroll
            for (int r = 0; r < 4; r++) iv[r] = 1.f / l_[r];
#pragma unroll
            for (int nt = 0; nt < 8; nt++)
#pragma unroll
                for (int r = 0; r < 4; r++) {
                    int t_ = q0 + wid * 16 + quad * 4 + r;
                    Y[((size_t)(b * 2048 + t_)) * 2048 + h * 128 + nt * 16 + l16] = f2bf(o[nt][r] * iv[r]);
                }
            q0 = (15 - qt) * 128;
            nit = NIT - nitA;
            il = 0;
#pragma unroll
            for (int kt = 0; kt < 4; kt++)
                qf[kt] = *(const short8*)&Qb[(size_t)(q0 + wid * 16 + l16) * 2048 + kt * 32 + quad * 8];
#pragma unroll
            for (int nt = 0; nt < 8; nt++) o[nt] = (f32x4){0.f, 0.f, 0.f, 0.f};
#pragma unroll
            for (int r = 0; r < 4; r++) { m_[r] = -1e30f; l_[r] = 0.f; }
        }
    }
    float iv[4];
#pragma unroll
    for (int r = 0; r < 4; r++) iv[r] = 1.f / l_[r];
#pragma unroll
    for (int nt = 0; nt < 8; nt++)
#pragma unroll
        for (int r = 0; r < 4; r++) {
            int t_ = q0 + wid * 16 + quad * 4 + r;
            Y[((size_t)(b * 2048 + t_)) * 2048 + h * 128 + nt * 16 + l16] = f2bf(o[nt][r] * iv[r]);
        }
}

extern "C" void kernel_launch(void* const* d_in, const int* in_sizes, int n_in,
                              void* d_out, int out_size, void* d_ws, size_t ws_size,
                              hipStream_t stream) {
    const float* x  = (const float*)d_in[0];
    const float* wq = (const float*)d_in[1];
    const float* wk = (const float*)d_in[2];
    const float* wv = (const float*)d_in[3];
    const float* wo = (const float*)d_in[4];
    const float* fc = (const float*)d_in[5];
    const float* fs = (const float*)d_in[6];
    float* out = (float*)d_out;

    char* ws = (char*)d_ws;
    float* s_vals   = (float*)ws;
    float* partials = (float*)(ws + 1024);
    u16* WT  = (u16*)(ws + 8192);
    u16* xb  = (u16*)(ws + 8192 + 8388608);
    u16* Qb  = xb + 8388608;
    u16* Kb  = Qb + 8388608;
    u16* VTb = Kb + 8388608;

    const float QSCALE = 0.08838834764831845f * 1.4426950408889634f;  // 1/sqrt(128)*log2(e)

    reduce1_kernel<<<256, 256, 0, stream>>>(wq, wk, wv, wo, partials);
    reduce2_kernel<<<1, 256, 0, stream>>>(partials, s_vals);
    cast_bf16_kernel<<<4096, 256, 0, stream>>>(x, xb);

    build_weff_kernel<<<1024, 256, 0, stream>>>(wq, s_vals + 0, WT);
    gemm_kernel<0><<<dim3(16, 32), 256, 0, stream>>>(xb, WT, s_vals + 0, Qb);
    rope_kernel<<<16384, 256, 0, stream>>>(Qb, fc, fs, QSCALE);

    build_weff_kernel<<<1024, 256, 0, stream>>>(wk, s_vals + 1, WT);
    gemm_kernel<0><<<dim3(16, 32), 256, 0, stream>>>(xb, WT, s_vals + 1, Kb);
    rope_kernel<<<16384, 256, 0, stream>>>(Kb, fc, fs, 1.0f);

    build_weff_kernel<<<1024, 256, 0, stream>>>(wv, s_vals + 2, WT);
    gemm_kernel<2><<<dim3(16, 32), 256, 0, stream>>>(xb, WT, s_vals + 2, VTb);

    flash_kernel<<<dim3(32, 8), 512, 0, stream>>>(Qb, Kb, VTb, Qb /* Y aliases Q: disjoint rows/cols */);

    build_weff_kernel<<<1024, 256, 0, stream>>>(wo, s_vals + 3, WT);
    gemm_kernel<1><<<dim3(16, 32), 256, 0, stream>>>(Qb, WT, s_vals + 3, (void*)out);
}